// Round 6
// baseline (4357.645 us; speedup 1.0000x reference)
//
#include <hip/hip_runtime.h>
#include <stdint.h>

// LSTM: B=128, T=512, I=256, H=512.
// R6: TWO-STREAM LATENCY HIDING. Evidence R0-R5: each agent-scope exchange
// leg (store-to-visible or poll-pass RT) costs ~600-900ns and the step time
// is serial latency, not bandwidth/congestion (R5 hint-line null killed the
// congestion theory; R3/R4 killed the XCD-L2 shortcut - incoherent). So:
// stop shrinking the legs, stop WAITING on them. Batches are independent:
// 4 sets x 32 WGs = 128 WGs; each WG runs TWO independent 16-batch streams
// in strict alternation A(t),B(t),A(t+1),... Stream A's publish->next-poll
// gap is filled by stream B's whole phase (and vice versa): steady cycle
// C = max(2*compute, compute+legs) instead of compute+legs per step.
// Weights (B-frags, VGPR-resident) are SHARED by both streams; per-stream
// persistent state is just c_reg. Exchange = R2-proven tagged-data scheme
// (64b word = tag<<32 | 2x bf16, [tbuf][colpair][batch] layout, relaxed
// agent scope, backoff poll). No hint line (R5: <=0). No sc0 (R4: broken).
// Deadlock audit: wait graph follows the strict global order A0,B0,A1,...;
// seeing h_A(t) from peer j implies j fully read h_A(t-1) (poll loads data
// into regs before j's next publish) -> all-consume-before-overwrite
// induction holds per stream; no circular waits.
// LDS partials: stream s uses part[s]; reuse across t is fenced by the
// OTHER stream's collective barrier (one __syncthreads per phase).

#define B_ 128
#define T_ 512
#define I_ 256
#define H_ 512
#define NB 16    // batches per stream

using short8 = __attribute__((ext_vector_type(8))) short;
using f32x4  = __attribute__((ext_vector_type(4))) float;

union V16 {
  uint32_t u[4];
  uint64_t q[2];
  short8 s;
};

__device__ __forceinline__ unsigned short bf16rne(float f) {
  uint32_t u = __builtin_bit_cast(uint32_t, f);
  u += 0x7fffu + ((u >> 16) & 1u);
  return (unsigned short)(u >> 16);
}

__device__ __forceinline__ short8 cvt8(float4 a, float4 b) {
  short8 r;
  r[0] = (short)bf16rne(a.x); r[1] = (short)bf16rne(a.y);
  r[2] = (short)bf16rne(a.z); r[3] = (short)bf16rne(a.w);
  r[4] = (short)bf16rne(b.x); r[5] = (short)bf16rne(b.y);
  r[6] = (short)bf16rne(b.z); r[7] = (short)bf16rne(b.w);
  return r;
}

__global__ __launch_bounds__(256, 1) void lstm_fused(
    const float* __restrict__ x,
    const float* __restrict__ Wi, const float* __restrict__ Ui, const float* __restrict__ bi,
    const float* __restrict__ Wf, const float* __restrict__ Uf, const float* __restrict__ bfv,
    const float* __restrict__ Wo, const float* __restrict__ Uo, const float* __restrict__ bo,
    const float* __restrict__ Wc, const float* __restrict__ Uc, const float* __restrict__ bc,
    float* __restrict__ out, uint32_t* __restrict__ ws)
{
  const int bid   = blockIdx.x;      // 0..127
  const int group = bid & 3;         // 4 sets
  const int wg    = bid >> 2;        // 0..31 within set
  const int tid   = threadIdx.x;
  const int lane  = tid & 63;
  const int wave  = tid >> 6;        // 0..3
  const int quad  = lane >> 4;       // 0..3
  const int row16 = lane & 15;       // A: batch row / B: output col
  const int bg0   = group * 32;      // set covers batches [bg0, bg0+32); stream s adds s*16
  const int col0  = wg * 16;

  // hbuf: [2 tbuf][256 colpairs][128 batches] tagged 64-bit words.
  // word = (tag<<32) | (bf16(col 2c+1)<<16) | bf16(col 2c).  512 KB total.
  // Streams touch disjoint batch columns -> no interference.
  uint64_t* hbuf = (uint64_t*)ws;

  // partials: [stream][m*16+n][16 floats (w*4+g)], row stride 20 dwords
  // => <=2-way bank aliasing (free) on both b128 store and read.
  __shared__ float part[2][256 * 20];

  const float* Wg[4] = {Wi, Wf, Wo, Wc};
  const float* Ug[4] = {Ui, Uf, Uo, Uc};

  // ---- resident B (weight) fragments: wave covers K in [wave*192, +192) ----
  // Shared by both streams (same output columns). B-frag 16x16x32: lane holds
  // B[k=quad*8+j][n=lane&15]; weights are [n][k] row-major.
  short8 bfr[6][4];
  const int kbase = wave * 192;
  #pragma unroll
  for (int ki = 0; ki < 6; ++ki) {
    const int kk = kbase + ki * 32;
    const int k  = kk + quad * 8;
    #pragma unroll
    for (int g = 0; g < 4; ++g) {
      const float* src = (kk < 512)
        ? (Wg[g] + (size_t)(col0 + row16) * H_ + k)
        : (Ug[g] + (size_t)(col0 + row16) * I_ + (k - 512));
      float4 lo = *(const float4*)src;
      float4 hi = *(const float4*)(src + 4);
      bfr[ki][g] = cvt8(lo, hi);
    }
  }

  // colpair word base per h-ki (batch offset added per stream at poll time):
  // lane needs cols kk+quad*8..+8 = colpairs kk/2+quad*4+{0..3}, each at
  // word (colpair*128 + batch); the 4 words are 128 words (1KB) apart.
  uint32_t cpw[6];
  #pragma unroll
  for (int ki = 0; ki < 6; ++ki) {
    const int kk = kbase + ki * 32;
    if (kk < 512)
      cpw[ki] = ((uint32_t)(kk >> 1) + (uint32_t)(quad << 2)) * 128u;
  }

  const int ub = tid >> 4;   // batch within stream (update phase)
  const int uc = tid & 15;   // col within WG tile
  const float* bptr[4] = {bi, bfv, bo, bc};
  float bias[4];
  #pragma unroll
  for (int g = 0; g < 4; ++g) bias[g] = bptr[g][col0 + uc];

  float c0 = 0.0f, c1 = 0.0f;   // per-stream cell state (named, not array)

  for (int t = 0; t < T_; ++t) {
    // ---- one phase per stream, strictly alternated ----
    auto phase = [&](const int s, float& c_s) {
      const int sb0 = bg0 + s * NB;          // this stream's batch base

      // -- prefetch x fragment (overlaps the poll below) --
      short8 afrag[6];
      #pragma unroll
      for (int ki = 0; ki < 6; ++ki) {
        const int kk = kbase + ki * 32;
        if (kk >= 512) {
          const int k = kk + quad * 8;
          const float* xp = x + ((size_t)(sb0 + row16) * T_ + t) * I_ + (k - 512);
          float4 lo = *(const float4*)xp;
          float4 hi = *(const float4*)(xp + 4);
          afrag[ki] = cvt8(lo, hi);
        }
      }

      // -- tagged-data poll: load h words, retry (backoff) until tags == t --
      if (t > 0) {
        if (kbase < 512) {                   // waves 0..2; wave 3 is x-only
          const uint32_t tgt = (uint32_t)t;
          uint64_t* hb = hbuf + (uint32_t)(t & 1) * 32768u;
          const uint32_t boff = (uint32_t)(sb0 + row16);
          V16 hv[6];
          bool ok;
          bool first = true;
          do {
            if (!first) __builtin_amdgcn_s_sleep(1);
            first = false;
            uint32_t bad = 0;
            #pragma unroll
            for (int ki = 0; ki < 6; ++ki) {
              if (kbase + ki * 32 < 512) {
                uint64_t* p = hb + cpw[ki] + boff;
                uint64_t q0 = __hip_atomic_load(p,       __ATOMIC_RELAXED, __HIP_MEMORY_SCOPE_AGENT);
                uint64_t q1 = __hip_atomic_load(p + 128, __ATOMIC_RELAXED, __HIP_MEMORY_SCOPE_AGENT);
                uint64_t q2 = __hip_atomic_load(p + 256, __ATOMIC_RELAXED, __HIP_MEMORY_SCOPE_AGENT);
                uint64_t q3 = __hip_atomic_load(p + 384, __ATOMIC_RELAXED, __HIP_MEMORY_SCOPE_AGENT);
                hv[ki].u[0] = (uint32_t)q0; hv[ki].u[1] = (uint32_t)q1;
                hv[ki].u[2] = (uint32_t)q2; hv[ki].u[3] = (uint32_t)q3;
                bad |= ((uint32_t)(q0 >> 32) ^ tgt) | ((uint32_t)(q1 >> 32) ^ tgt)
                     | ((uint32_t)(q2 >> 32) ^ tgt) | ((uint32_t)(q3 >> 32) ^ tgt);
              }
            }
            ok = (bad == 0);
          } while (!__all((int)ok));
          #pragma unroll
          for (int ki = 0; ki < 6; ++ki)
            if (kbase + ki * 32 < 512) afrag[ki] = hv[ki].s;
        }
      } else {
        #pragma unroll
        for (int ki = 0; ki < 6; ++ki) {
          if (kbase + ki * 32 < 512) {
            V16 z; z.q[0] = 0; z.q[1] = 0;
            afrag[ki] = z.s;
          }
        }
      }

      // -- MFMA: 6 K-iters x 4 gates --
      f32x4 acc[4] = {{0.f,0.f,0.f,0.f},{0.f,0.f,0.f,0.f},
                      {0.f,0.f,0.f,0.f},{0.f,0.f,0.f,0.f}};
      #pragma unroll
      for (int ki = 0; ki < 6; ++ki) {
        #pragma unroll
        for (int g = 0; g < 4; ++g)
          acc[g] = __builtin_amdgcn_mfma_f32_16x16x32_bf16(afrag[ki], bfr[ki][g], acc[g], 0, 0, 0);
      }

      // -- store partials transposed over gates: 4x b128, <=2-way banks --
      // C/D layout: n = lane&15, m = quad*4 + reg.
      float* pb = part[s];
      #pragma unroll
      for (int r = 0; r < 4; ++r) {
        f32x4 v;
        v[0] = acc[0][r]; v[1] = acc[1][r]; v[2] = acc[2][r]; v[3] = acc[3][r];
        *(f32x4*)&pb[(((quad << 2) + r) * 16 + row16) * 20 + (wave << 2)] = v;
      }
      __syncthreads();   // one barrier per phase; fences part[s] reuse across t

      // -- reduce: thread tid handles (m=ub, n=uc); row = tid; 4x b128 reads --
      const int rbase = tid * 20;
      f32x4 v0 = *(const f32x4*)&pb[rbase];
      f32x4 v1 = *(const f32x4*)&pb[rbase + 4];
      f32x4 v2 = *(const f32x4*)&pb[rbase + 8];
      f32x4 v3 = *(const f32x4*)&pb[rbase + 12];
      float pre[4];
      #pragma unroll
      for (int g = 0; g < 4; ++g)
        pre[g] = bias[g] + v0[g] + v1[g] + v2[g] + v3[g];

      const float ig = 1.0f / (1.0f + __expf(-pre[0]));
      const float fg = 1.0f / (1.0f + __expf(-pre[1]));
      const float og = 1.0f / (1.0f + __expf(-pre[2]));
      const float e2  = __expf(2.0f * pre[3]);
      const float ct  = (e2 - 1.0f) / (e2 + 1.0f);
      c_s = fg * c_s + ig * ct;
      const float e2c = __expf(2.0f * c_s);
      const float tc  = (e2c - 1.0f) / (e2c + 1.0f);
      const float h   = og * tc;

      if (t < T_ - 1) {
        // publish: tagged 64-bit store, fire-and-forget (legs elapse while
        // the WG runs the OTHER stream's phase).
        const float hpart = __shfl_xor(h, 1);
        if ((uc & 1) == 0) {
          const uint32_t d = (uint32_t)bf16rne(h) | ((uint32_t)bf16rne(hpart) << 16);
          const uint64_t qv = (uint64_t)d | ((uint64_t)(uint32_t)(t + 1) << 32);
          const uint32_t idx = (uint32_t)((t + 1) & 1) * 32768u
                             + (uint32_t)((col0 + uc) >> 1) * 128u
                             + (uint32_t)(sb0 + ub);
          __hip_atomic_store(hbuf + idx, qv, __ATOMIC_RELAXED, __HIP_MEMORY_SCOPE_AGENT);
        }
      } else {
        __builtin_nontemporal_store(
            h, &out[(size_t)B_ * T_ * H_ + (size_t)(sb0 + ub) * H_ + (col0 + uc)]);  // h_T
      }

      // hidden-seq store AFTER publish; nontemporal so the 134 MB stream
      // doesn't evict x / hbuf from the caches.
      __builtin_nontemporal_store(
          h, &out[((size_t)(sb0 + ub) * T_ + t) * H_ + (col0 + uc)]);
    };

    phase(0, c0);
    phase(1, c1);
  }

  // c_T (both streams)
  __builtin_nontemporal_store(
      c0, &out[(size_t)B_ * T_ * H_ + (size_t)B_ * H_ + (size_t)(bg0 + ub) * H_ + (col0 + uc)]);
  __builtin_nontemporal_store(
      c1, &out[(size_t)B_ * T_ * H_ + (size_t)B_ * H_ + (size_t)(bg0 + NB + ub) * H_ + (col0 + uc)]);
}

extern "C" void kernel_launch(void* const* d_in, const int* in_sizes, int n_in,
                              void* d_out, int out_size, void* d_ws, size_t ws_size,
                              hipStream_t stream) {
  // ws layout: [0, 512KB): double-buffered tagged h exchange
  //            [2 tbuf][256 colpairs][128 batches] x 8B words (tag in hi32;
  //            zeroed each launch so stale tags can never match t>=1).
  hipMemsetAsync(d_ws, 0, 2 * 256 * 128 * 8, stream);
  dim3 grid(128), block(256);
  lstm_fused<<<grid, block, 0, stream>>>(
      (const float*)d_in[0],
      (const float*)d_in[1], (const float*)d_in[2], (const float*)d_in[3],
      (const float*)d_in[4], (const float*)d_in[5], (const float*)d_in[6],
      (const float*)d_in[7], (const float*)d_in[8], (const float*)d_in[9],
      (const float*)d_in[10], (const float*)d_in[11], (const float*)d_in[12],
      (float*)d_out, (uint32_t*)d_ws);
}

// Round 7
// 2542.864 us; speedup vs baseline: 1.7137x; 1.7137x over previous
//
#include <hip/hip_runtime.h>
#include <stdint.h>

// LSTM: B=128, T=512, I=256, H=512.
// 8 groups (16 batches) x 32 WGs (16 h-cols) = 256 WGs, 1/CU.
// Weights [W|U] resident in VGPRs as MFMA B-frags (K-partitioned over 4 waves).
//
// R7 = R2 champion (2400us) + two serial-latency cuts. R6 falsified the
// "waiting for visibility" model: a full-phase gap between publish and poll
// did NOT shrink the stall -> the cost is in the poll EVENT + resync itself.
// Remaining suspects attacked here:
//  (a) __syncthreads lowers to s_waitcnt vmcnt(0) lgkmcnt(0): every step
//      serializes against the ack of the previous NT out-stores + publish
//      (vmcnt retires in issue order). The barrier only orders LDS partials
//      -> replaced with raw "s_waitcnt lgkmcnt(0); s_barrier" (LDS-only).
//      hbuf correctness is anchored in tags, not barrier order.
//  (b) s_sleep in the poll loop invites clock-gating; at MFMA 3% / VALU 17%
//      DVFS can halve the clock, stretching the whole chain. Busy-poll, no
//      sleep (R5 proved poll traffic volume is irrelevant).
// Exchange unchanged (R2-proven): tagged 64b words (tag<<32 | 2x bf16),
// [tbuf][colpair][batch] layout, relaxed agent scope; double-buffered hbuf;
// all-consume-before-next-publish induction. No sc0 (R4: stale-line trap),
// no hint line (R5: null), no two-stream alternation (R6: regression).

#define B_ 128
#define T_ 512
#define I_ 256
#define H_ 512
#define NB 16    // batches per group

using short8 = __attribute__((ext_vector_type(8))) short;
using f32x4  = __attribute__((ext_vector_type(4))) float;

union V16 {
  uint32_t u[4];
  uint64_t q[2];
  short8 s;
};

__device__ __forceinline__ unsigned short bf16rne(float f) {
  uint32_t u = __builtin_bit_cast(uint32_t, f);
  u += 0x7fffu + ((u >> 16) & 1u);
  return (unsigned short)(u >> 16);
}

__device__ __forceinline__ short8 cvt8(float4 a, float4 b) {
  short8 r;
  r[0] = (short)bf16rne(a.x); r[1] = (short)bf16rne(a.y);
  r[2] = (short)bf16rne(a.z); r[3] = (short)bf16rne(a.w);
  r[4] = (short)bf16rne(b.x); r[5] = (short)bf16rne(b.y);
  r[6] = (short)bf16rne(b.z); r[7] = (short)bf16rne(b.w);
  return r;
}

__global__ __launch_bounds__(256, 1) void lstm_fused(
    const float* __restrict__ x,
    const float* __restrict__ Wi, const float* __restrict__ Ui, const float* __restrict__ bi,
    const float* __restrict__ Wf, const float* __restrict__ Uf, const float* __restrict__ bfv,
    const float* __restrict__ Wo, const float* __restrict__ Uo, const float* __restrict__ bo,
    const float* __restrict__ Wc, const float* __restrict__ Uc, const float* __restrict__ bc,
    float* __restrict__ out, uint32_t* __restrict__ ws)
{
  const int bid   = blockIdx.x;
  const int group = bid & 7;        // XCD-locality heuristic only (not correctness)
  const int wg    = bid >> 3;       // 0..31 within group
  const int tid   = threadIdx.x;
  const int lane  = tid & 63;
  const int wave  = tid >> 6;       // 0..3
  const int quad  = lane >> 4;      // 0..3
  const int row16 = lane & 15;      // A: batch row / B: output col
  const int bg0   = group * NB;
  const int col0  = wg * 16;

  // hbuf: [2 tbuf][256 colpairs][128 batches] tagged 64-bit words.
  // word = (tag<<32) | (bf16(col 2c+1)<<16) | bf16(col 2c).  512 KB total.
  uint64_t* hbuf = (uint64_t*)ws;

  // partials: double-buffered [2][m*16+n][16 floats (w*4+g)], row stride 20
  // dwords => <=2-way bank aliasing (free) on both b128 store and read.
  __shared__ float part[2][256 * 20];

  const float* Wg[4] = {Wi, Wf, Wo, Wc};
  const float* Ug[4] = {Ui, Uf, Uo, Uc};

  // ---- resident B (weight) fragments: wave covers K in [wave*192, +192) ----
  // B-frag 16x16x32: lane holds B[k=quad*8+j][n=lane&15]; weights are [n][k] row-major.
  short8 bfr[6][4];
  const int kbase = wave * 192;
  #pragma unroll
  for (int ki = 0; ki < 6; ++ki) {
    const int kk = kbase + ki * 32;
    const int k  = kk + quad * 8;
    #pragma unroll
    for (int g = 0; g < 4; ++g) {
      const float* src = (kk < 512)
        ? (Wg[g] + (size_t)(col0 + row16) * H_ + k)
        : (Ug[g] + (size_t)(col0 + row16) * I_ + (k - 512));
      float4 lo = *(const float4*)src;
      float4 hi = *(const float4*)(src + 4);
      bfr[ki][g] = cvt8(lo, hi);
    }
  }

  // word index (sans buffer offset) for each h-carrying ki of this lane:
  // lane needs cols kk+quad*8..+8 = colpairs kk/2+quad*4+{0..3}, each at
  // word (colpair*128 + batch); the 4 words are 128 words (1KB) apart.
  uint32_t hidx[6];
  #pragma unroll
  for (int ki = 0; ki < 6; ++ki) {
    const int kk = kbase + ki * 32;
    if (kk < 512)
      hidx[ki] = ((uint32_t)(kk >> 1) + (uint32_t)(quad << 2)) * 128u
               + (uint32_t)(bg0 + row16);
  }

  const int ub = tid >> 4;   // batch within group (update phase)
  const int uc = tid & 15;   // col within WG tile
  const float* bptr[4] = {bi, bfv, bo, bc};
  float bias[4];
  #pragma unroll
  for (int g = 0; g < 4; ++g) bias[g] = bptr[g][col0 + uc];

  float c_reg = 0.0f;

  for (int t = 0; t < T_; ++t) {
    // ---- prefetch x fragment (overlaps with the poll below) ----
    short8 afrag[6];
    #pragma unroll
    for (int ki = 0; ki < 6; ++ki) {
      const int kk = kbase + ki * 32;
      if (kk >= 512) {
        const int k = kk + quad * 8;
        const float* xp = x + ((size_t)(bg0 + row16) * T_ + t) * I_ + (k - 512);
        float4 lo = *(const float4*)xp;
        float4 hi = *(const float4*)(xp + 4);
        afrag[ki] = cvt8(lo, hi);
      }
    }

    // ---- tagged-data poll: busy-retry (NO s_sleep) until all tags == t ----
    if (t > 0) {
      if (kbase < 512) {               // waves 0..2; wave 3 is x-only
        const uint32_t tgt = (uint32_t)t;
        uint64_t* hb = hbuf + (uint32_t)(t & 1) * 32768u;
        V16 hv[6];
        bool ok;
        do {
          uint32_t bad = 0;
          #pragma unroll
          for (int ki = 0; ki < 6; ++ki) {
            if (kbase + ki * 32 < 512) {
              uint64_t* p = hb + hidx[ki];
              uint64_t q0 = __hip_atomic_load(p,       __ATOMIC_RELAXED, __HIP_MEMORY_SCOPE_AGENT);
              uint64_t q1 = __hip_atomic_load(p + 128, __ATOMIC_RELAXED, __HIP_MEMORY_SCOPE_AGENT);
              uint64_t q2 = __hip_atomic_load(p + 256, __ATOMIC_RELAXED, __HIP_MEMORY_SCOPE_AGENT);
              uint64_t q3 = __hip_atomic_load(p + 384, __ATOMIC_RELAXED, __HIP_MEMORY_SCOPE_AGENT);
              hv[ki].u[0] = (uint32_t)q0; hv[ki].u[1] = (uint32_t)q1;
              hv[ki].u[2] = (uint32_t)q2; hv[ki].u[3] = (uint32_t)q3;
              bad |= ((uint32_t)(q0 >> 32) ^ tgt) | ((uint32_t)(q1 >> 32) ^ tgt)
                   | ((uint32_t)(q2 >> 32) ^ tgt) | ((uint32_t)(q3 >> 32) ^ tgt);
            }
          }
          ok = (bad == 0);
        } while (!__all((int)ok));
        #pragma unroll
        for (int ki = 0; ki < 6; ++ki)
          if (kbase + ki * 32 < 512) afrag[ki] = hv[ki].s;
      }
    } else {
      #pragma unroll
      for (int ki = 0; ki < 6; ++ki) {
        if (kbase + ki * 32 < 512) {
          V16 z; z.q[0] = 0; z.q[1] = 0;
          afrag[ki] = z.s;
        }
      }
    }

    // ---- MFMA: 6 K-iters x 4 gates ----
    f32x4 acc[4] = {{0.f,0.f,0.f,0.f},{0.f,0.f,0.f,0.f},
                    {0.f,0.f,0.f,0.f},{0.f,0.f,0.f,0.f}};
    #pragma unroll
    for (int ki = 0; ki < 6; ++ki) {
      #pragma unroll
      for (int g = 0; g < 4; ++g)
        acc[g] = __builtin_amdgcn_mfma_f32_16x16x32_bf16(afrag[ki], bfr[ki][g], acc[g], 0, 0, 0);
    }

    // ---- store partials transposed over gates: 4x b128, <=2-way banks ----
    // C/D layout: n = lane&15, m = quad*4 + reg.
    float* pb = part[t & 1];
    #pragma unroll
    for (int r = 0; r < 4; ++r) {
      f32x4 v;
      v[0] = acc[0][r]; v[1] = acc[1][r]; v[2] = acc[2][r]; v[3] = acc[3][r];
      *(f32x4*)&pb[(((quad << 2) + r) * 16 + row16) * 20 + (wave << 2)] = v;
    }

    // ---- LDS-only barrier: NO vmcnt(0) drain (the __syncthreads lowering
    // would serialize against NT-store/publish acks; only LDS ordering is
    // needed here — hbuf correctness is carried by the tags).
    asm volatile("s_waitcnt lgkmcnt(0)\n\ts_barrier" ::: "memory");

    // ---- reduce: thread tid handles (m=ub, n=uc); row = tid; 4x b128 reads ----
    const int rbase = tid * 20;
    f32x4 v0 = *(const f32x4*)&pb[rbase];
    f32x4 v1 = *(const f32x4*)&pb[rbase + 4];
    f32x4 v2 = *(const f32x4*)&pb[rbase + 8];
    f32x4 v3 = *(const f32x4*)&pb[rbase + 12];
    float pre[4];
    #pragma unroll
    for (int g = 0; g < 4; ++g)
      pre[g] = bias[g] + v0[g] + v1[g] + v2[g] + v3[g];

    const float ig = 1.0f / (1.0f + __expf(-pre[0]));
    const float fg = 1.0f / (1.0f + __expf(-pre[1]));
    const float og = 1.0f / (1.0f + __expf(-pre[2]));
    const float e2  = __expf(2.0f * pre[3]);
    const float ct  = (e2 - 1.0f) / (e2 + 1.0f);
    c_reg = fg * c_reg + ig * ct;
    const float e2c = __expf(2.0f * c_reg);
    const float tc  = (e2c - 1.0f) / (e2c + 1.0f);
    const float h   = og * tc;

    if (t < T_ - 1) {
      // publish: tagged 64-bit store, fire-and-forget.
      const float hpart = __shfl_xor(h, 1);
      if ((uc & 1) == 0) {
        const uint32_t d = (uint32_t)bf16rne(h) | ((uint32_t)bf16rne(hpart) << 16);
        const uint64_t qv = (uint64_t)d | ((uint64_t)(uint32_t)(t + 1) << 32);
        const uint32_t idx = (uint32_t)((t + 1) & 1) * 32768u
                           + (uint32_t)((col0 + uc) >> 1) * 128u
                           + (uint32_t)(bg0 + ub);
        __hip_atomic_store(hbuf + idx, qv, __ATOMIC_RELAXED, __HIP_MEMORY_SCOPE_AGENT);
      }
    } else {
      __builtin_nontemporal_store(
          h, &out[(size_t)B_ * T_ * H_ + (size_t)(bg0 + ub) * H_ + (col0 + uc)]);  // h_T
    }

    // hidden-seq store AFTER publish; nontemporal so the 134 MB stream doesn't
    // evict x / hbuf from the caches.
    __builtin_nontemporal_store(
        h, &out[((size_t)(bg0 + ub) * T_ + t) * H_ + (col0 + uc)]);
  }

  // c_T
  __builtin_nontemporal_store(
      c_reg, &out[(size_t)B_ * T_ * H_ + (size_t)B_ * H_ + (size_t)(bg0 + ub) * H_ + (col0 + uc)]);
}

extern "C" void kernel_launch(void* const* d_in, const int* in_sizes, int n_in,
                              void* d_out, int out_size, void* d_ws, size_t ws_size,
                              hipStream_t stream) {
  // ws layout: [0, 512KB): double-buffered tagged h exchange
  //            [2 tbuf][256 colpairs][128 batches] x 8B words (tag in hi32;
  //            zeroed each launch so stale tags can never match t>=1).
  hipMemsetAsync(d_ws, 0, 2 * 256 * 128 * 8, stream);
  dim3 grid(256), block(256);
  lstm_fused<<<grid, block, 0, stream>>>(
      (const float*)d_in[0],
      (const float*)d_in[1], (const float*)d_in[2], (const float*)d_in[3],
      (const float*)d_in[4], (const float*)d_in[5], (const float*)d_in[6],
      (const float*)d_in[7], (const float*)d_in[8], (const float*)d_in[9],
      (const float*)d_in[10], (const float*)d_in[11], (const float*)d_in[12],
      (float*)d_out, (uint32_t*)d_ws);
}

// Round 9
// 2019.523 us; speedup vs baseline: 2.1578x; 1.2591x over previous
//
#include <hip/hip_runtime.h>
#include <stdint.h>

// LSTM: B=128, T=512, I=256, H=512.
// 8 groups (16 batches) x 32 WGs (16 h-cols) = 256 WGs, 1/CU.
// Weights [W|U] resident in VGPRs as MFMA B-frags (K-partitioned over 4 waves).
//
// R9 = R8 (store/poll wave specialization) with the compile fix: NT stores
// use ext_vector f32x4, not HIP_vector_type float4 (builtin rejects it).
// Theory unchanged: vmcnt retires IN ISSUE ORDER, so each step's poll
// s_waitcnt vmcnt(0) inherits the PREVIOUS step's NT-store + publish acks
// (HBM-bound, ~1-3us under write pressure). vmcnt is PER-WAVE -> wave 3
// (all-x K range, never polls) becomes the only store-issuing wave: after
// reduce, all threads drop h into LDS (hsh[256]); wave 3 gathers
// (ds_read_b128), packs + publishes tagged words, issues hidden-seq/h_T NT
// stores. Waves 0-2 issue ZERO global stores in the loop -> load-only
// vmcnt waits. Wave 3's x loads: double-buffered RAW (cvt deferred one
// step), new loads issued BEFORE its stores -> its waits never inherit
// store acks either. Sync topology unchanged (tagged-data induction
// identical; publish moves after a new LDS-only barrier2 = still after
// this WG consumed h(t)).
// Exchange (R2-proven): tagged 64b words (tag<<32|2x bf16), [tbuf][colpair]
// [batch], relaxed agent scope, busy poll. No sc0 (R4), no hint (R5), no
// stream-alternation (R6), LDS-only barriers (R7, neutral but principled).

#define B_ 128
#define T_ 512
#define I_ 256
#define H_ 512
#define NB 16    // batches per group

using short8 = __attribute__((ext_vector_type(8))) short;
using f32x4  = __attribute__((ext_vector_type(4))) float;

union V16 {
  uint32_t u[4];
  uint64_t q[2];
  short8 s;
};

__device__ __forceinline__ unsigned short bf16rne(float f) {
  uint32_t u = __builtin_bit_cast(uint32_t, f);
  u += 0x7fffu + ((u >> 16) & 1u);
  return (unsigned short)(u >> 16);
}

__device__ __forceinline__ short8 cvt8(float4 a, float4 b) {
  short8 r;
  r[0] = (short)bf16rne(a.x); r[1] = (short)bf16rne(a.y);
  r[2] = (short)bf16rne(a.z); r[3] = (short)bf16rne(a.w);
  r[4] = (short)bf16rne(b.x); r[5] = (short)bf16rne(b.y);
  r[6] = (short)bf16rne(b.z); r[7] = (short)bf16rne(b.w);
  return r;
}

__global__ __launch_bounds__(256, 1) void lstm_fused(
    const float* __restrict__ x,
    const float* __restrict__ Wi, const float* __restrict__ Ui, const float* __restrict__ bi,
    const float* __restrict__ Wf, const float* __restrict__ Uf, const float* __restrict__ bfv,
    const float* __restrict__ Wo, const float* __restrict__ Uo, const float* __restrict__ bo,
    const float* __restrict__ Wc, const float* __restrict__ Uc, const float* __restrict__ bc,
    float* __restrict__ out, uint32_t* __restrict__ ws)
{
  const int bid   = blockIdx.x;
  const int group = bid & 7;        // XCD-locality heuristic only (not correctness)
  const int wg    = bid >> 3;       // 0..31 within group
  const int tid   = threadIdx.x;
  const int lane  = tid & 63;
  const int wave  = tid >> 6;       // 0..3
  const int quad  = lane >> 4;      // 0..3
  const int row16 = lane & 15;      // A: batch row / B: output col
  const int bg0   = group * NB;
  const int col0  = wg * 16;

  // hbuf: [2 tbuf][256 colpairs][128 batches] tagged 64-bit words.
  // word = (tag<<32) | (bf16(col 2c+1)<<16) | bf16(col 2c).  512 KB total.
  uint64_t* hbuf = (uint64_t*)ws;

  // partials: double-buffered [2][m*16+n][16 floats (w*4+g)], row stride 20
  // dwords => <=2-way bank aliasing (free) on both b128 store and read.
  __shared__ float part[2][256 * 20];
  // h staging for the store wave: hsh[ub*16+uc].
  __shared__ float hsh[256];

  const float* Wg[4] = {Wi, Wf, Wo, Wc};
  const float* Ug[4] = {Ui, Uf, Uo, Uc};

  // ---- resident B (weight) fragments: wave covers K in [wave*192, +192) ----
  // wave 0: K 0..191 (h), wave 1: 192..383 (h), wave 2: 384..543 (h)+512..575(x),
  // wave 3: 576..767 (all x). B-frag 16x16x32: lane holds B[k=quad*8+j][n=lane&15].
  short8 bfr[6][4];
  const int kbase = wave * 192;
  #pragma unroll
  for (int ki = 0; ki < 6; ++ki) {
    const int kk = kbase + ki * 32;
    const int k  = kk + quad * 8;
    #pragma unroll
    for (int g = 0; g < 4; ++g) {
      const float* src = (kk < 512)
        ? (Wg[g] + (size_t)(col0 + row16) * H_ + k)
        : (Ug[g] + (size_t)(col0 + row16) * I_ + (k - 512));
      float4 lo = *(const float4*)src;
      float4 hi = *(const float4*)(src + 4);
      bfr[ki][g] = cvt8(lo, hi);
    }
  }

  // poll word index per h-ki (waves 0-2): colpairs kk/2+quad*4+{0..3}, each
  // at word (colpair*128 + batch); the 4 words are 128 words (1KB) apart.
  uint32_t hidx[6];
  #pragma unroll
  for (int ki = 0; ki < 6; ++ki) {
    const int kk = kbase + ki * 32;
    if (kk < 512)
      hidx[ki] = ((uint32_t)(kk >> 1) + (uint32_t)(quad << 2)) * 128u
               + (uint32_t)(bg0 + row16);
  }

  const int ub = tid >> 4;   // batch within group (update phase)
  const int uc = tid & 15;   // col within WG tile
  const float* bptr[4] = {bi, bfv, bo, bc};
  float bias[4];
  #pragma unroll
  for (int g = 0; g < 4; ++g) bias[g] = bptr[g][col0 + uc];

  float c_reg = 0.0f;

  short8 afrag[6];           // A fragments (persist across steps for wave 3)
  float4 xlo[6], xhi[6];     // wave 3: RAW x(t+1) (cvt deferred one step)

  // ---- wave-3 prologue: afrag = x(0) converted; xraw = x(1) issued ----
  if (wave == 3) {
    #pragma unroll
    for (int ki = 0; ki < 6; ++ki) {
      const int k = kbase + ki * 32 + quad * 8 - 512;
      const float* xp0 = x + ((size_t)(bg0 + row16) * T_ + 0) * I_ + k;
      afrag[ki] = cvt8(*(const float4*)xp0, *(const float4*)(xp0 + 4));
      const float* xp1 = x + ((size_t)(bg0 + row16) * T_ + 1) * I_ + k;
      xlo[ki] = *(const float4*)xp1;
      xhi[ki] = *(const float4*)(xp1 + 4);
    }
  }

  for (int t = 0; t < T_; ++t) {
    // ---- x prefetch for waves 0-2 (only wave 2 has kk>=512 ki) ----
    if (wave < 3) {
      #pragma unroll
      for (int ki = 0; ki < 6; ++ki) {
        const int kk = kbase + ki * 32;
        if (kk >= 512) {
          const int k = kk + quad * 8;
          const float* xp = x + ((size_t)(bg0 + row16) * T_ + t) * I_ + (k - 512);
          float4 lo = *(const float4*)xp;
          float4 hi = *(const float4*)(xp + 4);
          afrag[ki] = cvt8(lo, hi);
        }
      }
    }

    // ---- tagged-data poll (waves 0-2): busy-retry until all tags == t ----
    // These waves issue NO stores -> vmcnt waits here are load-only.
    if (t > 0) {
      if (kbase < 512) {
        const uint32_t tgt = (uint32_t)t;
        uint64_t* hb = hbuf + (uint32_t)(t & 1) * 32768u;
        V16 hv[6];
        bool ok;
        do {
          uint32_t bad = 0;
          #pragma unroll
          for (int ki = 0; ki < 6; ++ki) {
            if (kbase + ki * 32 < 512) {
              uint64_t* p = hb + hidx[ki];
              uint64_t q0 = __hip_atomic_load(p,       __ATOMIC_RELAXED, __HIP_MEMORY_SCOPE_AGENT);
              uint64_t q1 = __hip_atomic_load(p + 128, __ATOMIC_RELAXED, __HIP_MEMORY_SCOPE_AGENT);
              uint64_t q2 = __hip_atomic_load(p + 256, __ATOMIC_RELAXED, __HIP_MEMORY_SCOPE_AGENT);
              uint64_t q3 = __hip_atomic_load(p + 384, __ATOMIC_RELAXED, __HIP_MEMORY_SCOPE_AGENT);
              hv[ki].u[0] = (uint32_t)q0; hv[ki].u[1] = (uint32_t)q1;
              hv[ki].u[2] = (uint32_t)q2; hv[ki].u[3] = (uint32_t)q3;
              bad |= ((uint32_t)(q0 >> 32) ^ tgt) | ((uint32_t)(q1 >> 32) ^ tgt)
                   | ((uint32_t)(q2 >> 32) ^ tgt) | ((uint32_t)(q3 >> 32) ^ tgt);
            }
          }
          ok = (bad == 0);
        } while (!__all((int)ok));
        #pragma unroll
        for (int ki = 0; ki < 6; ++ki)
          if (kbase + ki * 32 < 512) afrag[ki] = hv[ki].s;
      }
    } else {
      #pragma unroll
      for (int ki = 0; ki < 6; ++ki) {
        if (kbase + ki * 32 < 512) {
          V16 z; z.q[0] = 0; z.q[1] = 0;
          afrag[ki] = z.s;
        }
      }
    }

    // ---- MFMA: 6 K-iters x 4 gates ----
    f32x4 acc[4] = {{0.f,0.f,0.f,0.f},{0.f,0.f,0.f,0.f},
                    {0.f,0.f,0.f,0.f},{0.f,0.f,0.f,0.f}};
    #pragma unroll
    for (int ki = 0; ki < 6; ++ki) {
      #pragma unroll
      for (int g = 0; g < 4; ++g)
        acc[g] = __builtin_amdgcn_mfma_f32_16x16x32_bf16(afrag[ki], bfr[ki][g], acc[g], 0, 0, 0);
    }

    // ---- store partials transposed over gates: 4x b128, <=2-way banks ----
    // C/D layout: n = lane&15, m = quad*4 + reg.
    float* pb = part[t & 1];
    #pragma unroll
    for (int r = 0; r < 4; ++r) {
      f32x4 v;
      v[0] = acc[0][r]; v[1] = acc[1][r]; v[2] = acc[2][r]; v[3] = acc[3][r];
      *(f32x4*)&pb[(((quad << 2) + r) * 16 + row16) * 20 + (wave << 2)] = v;
    }
    // LDS-only barrier (no vmcnt drain)
    asm volatile("s_waitcnt lgkmcnt(0)\n\ts_barrier" ::: "memory");

    // ---- reduce: thread tid handles (m=ub, n=uc); row = tid; 4x b128 reads ----
    const int rbase = tid * 20;
    f32x4 v0 = *(const f32x4*)&pb[rbase];
    f32x4 v1 = *(const f32x4*)&pb[rbase + 4];
    f32x4 v2 = *(const f32x4*)&pb[rbase + 8];
    f32x4 v3 = *(const f32x4*)&pb[rbase + 12];
    float pre[4];
    #pragma unroll
    for (int g = 0; g < 4; ++g)
      pre[g] = bias[g] + v0[g] + v1[g] + v2[g] + v3[g];

    const float ig = 1.0f / (1.0f + __expf(-pre[0]));
    const float fg = 1.0f / (1.0f + __expf(-pre[1]));
    const float og = 1.0f / (1.0f + __expf(-pre[2]));
    const float e2  = __expf(2.0f * pre[3]);
    const float ct  = (e2 - 1.0f) / (e2 + 1.0f);
    c_reg = fg * c_reg + ig * ct;
    const float e2c = __expf(2.0f * c_reg);
    const float tc  = (e2c - 1.0f) / (e2c + 1.0f);
    const float h   = og * tc;

    // hand h to the store wave
    hsh[tid] = h;
    asm volatile("s_waitcnt lgkmcnt(0)\n\ts_barrier" ::: "memory");

    // ---- wave 3: rotate x, issue next x loads, then ALL global stores ----
    if (wave == 3) {
      // rotate: cvt the raw x(t+1) loaded a full step ago (no load stall)
      if (t + 1 < T_) {
        #pragma unroll
        for (int ki = 0; ki < 6; ++ki) afrag[ki] = cvt8(xlo[ki], xhi[ki]);
      }
      // issue raw x(t+2) BEFORE stores: later waits for these loads never
      // inherit store acks (in-order vmcnt retirement).
      if (t + 2 < T_) {
        #pragma unroll
        for (int ki = 0; ki < 6; ++ki) {
          const int k = kbase + ki * 32 + quad * 8 - 512;
          const float* xp = x + ((size_t)(bg0 + row16) * T_ + (t + 2)) * I_ + k;
          xlo[ki] = *(const float4*)xp;
          xhi[ki] = *(const float4*)(xp + 4);
        }
      }
      // gather h: lane l -> (ub=l>>2, uc=4*(l&3)..+3), one ds_read_b128
      const f32x4 hv4 = *(const f32x4*)&hsh[(lane >> 2) * 16 + (lane & 3) * 4];
      // publish FIRST (critical path for consumers)
      if (t < T_ - 1) {
        const uint32_t d0 = (uint32_t)bf16rne(hv4[0]) | ((uint32_t)bf16rne(hv4[1]) << 16);
        const uint32_t d1 = (uint32_t)bf16rne(hv4[2]) | ((uint32_t)bf16rne(hv4[3]) << 16);
        const uint64_t tag = ((uint64_t)(uint32_t)(t + 1)) << 32;
        const uint32_t idx0 = (uint32_t)((t + 1) & 1) * 32768u
                            + ((uint32_t)(col0 >> 1) + 2u * (uint32_t)(lane & 3)) * 128u
                            + (uint32_t)(bg0 + (lane >> 2));
        __hip_atomic_store(hbuf + idx0,       (uint64_t)d0 | tag, __ATOMIC_RELAXED, __HIP_MEMORY_SCOPE_AGENT);
        __hip_atomic_store(hbuf + idx0 + 128, (uint64_t)d1 | tag, __ATOMIC_RELAXED, __HIP_MEMORY_SCOPE_AGENT);
      }
      // hidden-seq row t (NT, 16B/lane, 64B per 4-lane cluster)
      f32x4* op = (f32x4*)&out[((size_t)(bg0 + (lane >> 2)) * T_ + t) * H_ + col0 + 4 * (lane & 3)];
      __builtin_nontemporal_store(hv4, op);
      if (t == T_ - 1) {
        f32x4* hp = (f32x4*)&out[(size_t)B_ * T_ * H_ + (size_t)(bg0 + (lane >> 2)) * H_ + col0 + 4 * (lane & 3)];
        __builtin_nontemporal_store(hv4, hp);   // h_T
      }
    }
  }

  // c_T (per-thread; after the loop, nothing polls anymore)
  __builtin_nontemporal_store(
      c_reg, &out[(size_t)B_ * T_ * H_ + (size_t)B_ * H_ + (size_t)(bg0 + ub) * H_ + (col0 + uc)]);
}

extern "C" void kernel_launch(void* const* d_in, const int* in_sizes, int n_in,
                              void* d_out, int out_size, void* d_ws, size_t ws_size,
                              hipStream_t stream) {
  // ws layout: [0, 512KB): double-buffered tagged h exchange
  //            [2 tbuf][256 colpairs][128 batches] x 8B words (tag in hi32;
  //            zeroed each launch so stale tags can never match t>=1).
  hipMemsetAsync(d_ws, 0, 2 * 256 * 128 * 8, stream);
  dim3 grid(256), block(256);
  lstm_fused<<<grid, block, 0, stream>>>(
      (const float*)d_in[0],
      (const float*)d_in[1], (const float*)d_in[2], (const float*)d_in[3],
      (const float*)d_in[4], (const float*)d_in[5], (const float*)d_in[6],
      (const float*)d_in[7], (const float*)d_in[8], (const float*)d_in[9],
      (const float*)d_in[10], (const float*)d_in[11], (const float*)d_in[12],
      (float*)d_out, (uint32_t*)d_ws);
}

// Round 11
// 1887.385 us; speedup vs baseline: 2.3088x; 1.0700x over previous
//
#include <hip/hip_runtime.h>
#include <stdint.h>

// LSTM: B=128, T=512, I=256, H=512.
// 8 groups (16 batches) x 32 WGs (16 h-cols) = 256 WGs, 1/CU.
// Weights [W|U] resident in VGPRs as MFMA B-frags (K-partitioned over 4 waves).
//
// R11 = R9 (1915us, proven) + EARLY PUBLISH with IDEMPOTENT RE-PUBLISH.
// R10 (early publish only) hit "container failed twice" with no compile
// error -> hang or flake; sync audit found no deadlock (publish of tag t+1
// still follows the WG's completed poll of tag t -> overwrite induction
// holds). Hedged retest: compute threads publish their tagged word right
// after gate math (store-to-visible latency, the longest remaining leg per
// R9 accounting, starts elapsing a full compute-phase earlier), AND wave 3
// re-publishes the IDENTICAL words post-barrier2 exactly as in R9 (same
// addr, same value -> idempotent; no new race; if the early store is
// lost/delayed the R9-proven path still delivers).
// Everything else byte-identical to R9: wave 3 = sole NT-store wave
// (hidden-seq/h_T), waves 0-2 loop-global-store-free except the 8B publish;
// wave-3 x loads double-buffered raw, issued before its stores (in-order
// vmcnt never inherits store acks). Exchange: R2-proven tagged 64b words
// (tag<<32|2x bf16), [tbuf][colpair][batch], relaxed agent scope, busy
// poll, double-buffered hbuf + all-consume-before-next-publish induction.
// LDS-only barriers. No sc0 (R4), no hint (R5), no stream-alt (R6).

#define B_ 128
#define T_ 512
#define I_ 256
#define H_ 512
#define NB 16    // batches per group

using short8 = __attribute__((ext_vector_type(8))) short;
using f32x4  = __attribute__((ext_vector_type(4))) float;

union V16 {
  uint32_t u[4];
  uint64_t q[2];
  short8 s;
};

__device__ __forceinline__ unsigned short bf16rne(float f) {
  uint32_t u = __builtin_bit_cast(uint32_t, f);
  u += 0x7fffu + ((u >> 16) & 1u);
  return (unsigned short)(u >> 16);
}

__device__ __forceinline__ short8 cvt8(float4 a, float4 b) {
  short8 r;
  r[0] = (short)bf16rne(a.x); r[1] = (short)bf16rne(a.y);
  r[2] = (short)bf16rne(a.z); r[3] = (short)bf16rne(a.w);
  r[4] = (short)bf16rne(b.x); r[5] = (short)bf16rne(b.y);
  r[6] = (short)bf16rne(b.z); r[7] = (short)bf16rne(b.w);
  return r;
}

__global__ __launch_bounds__(256, 1) void lstm_fused(
    const float* __restrict__ x,
    const float* __restrict__ Wi, const float* __restrict__ Ui, const float* __restrict__ bi,
    const float* __restrict__ Wf, const float* __restrict__ Uf, const float* __restrict__ bfv,
    const float* __restrict__ Wo, const float* __restrict__ Uo, const float* __restrict__ bo,
    const float* __restrict__ Wc, const float* __restrict__ Uc, const float* __restrict__ bc,
    float* __restrict__ out, uint32_t* __restrict__ ws)
{
  const int bid   = blockIdx.x;
  const int group = bid & 7;        // XCD-locality heuristic only (not correctness)
  const int wg    = bid >> 3;       // 0..31 within group
  const int tid   = threadIdx.x;
  const int lane  = tid & 63;
  const int wave  = tid >> 6;       // 0..3
  const int quad  = lane >> 4;      // 0..3
  const int row16 = lane & 15;      // A: batch row / B: output col
  const int bg0   = group * NB;
  const int col0  = wg * 16;

  // hbuf: [2 tbuf][256 colpairs][128 batches] tagged 64-bit words.
  // word = (tag<<32) | (bf16(col 2c+1)<<16) | bf16(col 2c).  512 KB total.
  uint64_t* hbuf = (uint64_t*)ws;

  // partials: double-buffered [2][m*16+n][16 floats (w*4+g)], row stride 20
  // dwords => <=2-way bank aliasing (free) on both b128 store and read.
  __shared__ float part[2][256 * 20];
  // h staging for the store wave: hsh[ub*16+uc].
  __shared__ float hsh[256];

  const float* Wg[4] = {Wi, Wf, Wo, Wc};
  const float* Ug[4] = {Ui, Uf, Uo, Uc};

  // ---- resident B (weight) fragments: wave covers K in [wave*192, +192) ----
  // waves 0-1: all h; wave 2: 4 h + 2 x; wave 3: all x.
  // B-frag 16x16x32: lane holds B[k=quad*8+j][n=lane&15].
  short8 bfr[6][4];
  const int kbase = wave * 192;
  #pragma unroll
  for (int ki = 0; ki < 6; ++ki) {
    const int kk = kbase + ki * 32;
    const int k  = kk + quad * 8;
    #pragma unroll
    for (int g = 0; g < 4; ++g) {
      const float* src = (kk < 512)
        ? (Wg[g] + (size_t)(col0 + row16) * H_ + k)
        : (Ug[g] + (size_t)(col0 + row16) * I_ + (k - 512));
      float4 lo = *(const float4*)src;
      float4 hi = *(const float4*)(src + 4);
      bfr[ki][g] = cvt8(lo, hi);
    }
  }

  // poll word index per h-ki (waves 0-2): colpairs kk/2+quad*4+{0..3}, each
  // at word (colpair*128 + batch); the 4 words are 128 words (1KB) apart.
  uint32_t hidx[6];
  #pragma unroll
  for (int ki = 0; ki < 6; ++ki) {
    const int kk = kbase + ki * 32;
    if (kk < 512)
      hidx[ki] = ((uint32_t)(kk >> 1) + (uint32_t)(quad << 2)) * 128u
               + (uint32_t)(bg0 + row16);
  }

  const int ub = tid >> 4;   // batch within group (update phase)
  const int uc = tid & 15;   // col within WG tile
  const float* bptr[4] = {bi, bfv, bo, bc};
  float bias[4];
  #pragma unroll
  for (int g = 0; g < 4; ++g) bias[g] = bptr[g][col0 + uc];

  float c_reg = 0.0f;

  short8 afrag[6];           // A fragments (persist across steps for wave 3)
  float4 xlo[6], xhi[6];     // wave 3: RAW x(t+1) (cvt deferred one step)

  // ---- wave-3 prologue: afrag = x(0) converted; xraw = x(1) issued ----
  if (wave == 3) {
    #pragma unroll
    for (int ki = 0; ki < 6; ++ki) {
      const int k = kbase + ki * 32 + quad * 8 - 512;
      const float* xp0 = x + ((size_t)(bg0 + row16) * T_ + 0) * I_ + k;
      afrag[ki] = cvt8(*(const float4*)xp0, *(const float4*)(xp0 + 4));
      const float* xp1 = x + ((size_t)(bg0 + row16) * T_ + 1) * I_ + k;
      xlo[ki] = *(const float4*)xp1;
      xhi[ki] = *(const float4*)(xp1 + 4);
    }
  }

  for (int t = 0; t < T_; ++t) {
    // ---- x prefetch for waves 0-2 (only wave 2 has kk>=512 ki) ----
    if (wave < 3) {
      #pragma unroll
      for (int ki = 0; ki < 6; ++ki) {
        const int kk = kbase + ki * 32;
        if (kk >= 512) {
          const int k = kk + quad * 8;
          const float* xp = x + ((size_t)(bg0 + row16) * T_ + t) * I_ + (k - 512);
          float4 lo = *(const float4*)xp;
          float4 hi = *(const float4*)(xp + 4);
          afrag[ki] = cvt8(lo, hi);
        }
      }
    }

    // ---- tagged-data poll (waves 0-2): busy-retry until all tags == t ----
    // Waves 0-2 issue only the 8B early publish per step -> their vmcnt
    // waits here never inherit HBM NT-store acks (R9's win).
    if (t > 0) {
      if (kbase < 512) {
        const uint32_t tgt = (uint32_t)t;
        uint64_t* hb = hbuf + (uint32_t)(t & 1) * 32768u;
        V16 hv[6];
        bool ok;
        do {
          uint32_t bad = 0;
          #pragma unroll
          for (int ki = 0; ki < 6; ++ki) {
            if (kbase + ki * 32 < 512) {
              uint64_t* p = hb + hidx[ki];
              uint64_t q0 = __hip_atomic_load(p,       __ATOMIC_RELAXED, __HIP_MEMORY_SCOPE_AGENT);
              uint64_t q1 = __hip_atomic_load(p + 128, __ATOMIC_RELAXED, __HIP_MEMORY_SCOPE_AGENT);
              uint64_t q2 = __hip_atomic_load(p + 256, __ATOMIC_RELAXED, __HIP_MEMORY_SCOPE_AGENT);
              uint64_t q3 = __hip_atomic_load(p + 384, __ATOMIC_RELAXED, __HIP_MEMORY_SCOPE_AGENT);
              hv[ki].u[0] = (uint32_t)q0; hv[ki].u[1] = (uint32_t)q1;
              hv[ki].u[2] = (uint32_t)q2; hv[ki].u[3] = (uint32_t)q3;
              bad |= ((uint32_t)(q0 >> 32) ^ tgt) | ((uint32_t)(q1 >> 32) ^ tgt)
                   | ((uint32_t)(q2 >> 32) ^ tgt) | ((uint32_t)(q3 >> 32) ^ tgt);
            }
          }
          ok = (bad == 0);
        } while (!__all((int)ok));
        #pragma unroll
        for (int ki = 0; ki < 6; ++ki)
          if (kbase + ki * 32 < 512) afrag[ki] = hv[ki].s;
      }
    } else {
      #pragma unroll
      for (int ki = 0; ki < 6; ++ki) {
        if (kbase + ki * 32 < 512) {
          V16 z; z.q[0] = 0; z.q[1] = 0;
          afrag[ki] = z.s;
        }
      }
    }

    // ---- MFMA: 6 K-iters x 4 gates ----
    f32x4 acc[4] = {{0.f,0.f,0.f,0.f},{0.f,0.f,0.f,0.f},
                    {0.f,0.f,0.f,0.f},{0.f,0.f,0.f,0.f}};
    #pragma unroll
    for (int ki = 0; ki < 6; ++ki) {
      #pragma unroll
      for (int g = 0; g < 4; ++g)
        acc[g] = __builtin_amdgcn_mfma_f32_16x16x32_bf16(afrag[ki], bfr[ki][g], acc[g], 0, 0, 0);
    }

    // ---- store partials transposed over gates: 4x b128, <=2-way banks ----
    // C/D layout: n = lane&15, m = quad*4 + reg.
    float* pb = part[t & 1];
    #pragma unroll
    for (int r = 0; r < 4; ++r) {
      f32x4 v;
      v[0] = acc[0][r]; v[1] = acc[1][r]; v[2] = acc[2][r]; v[3] = acc[3][r];
      *(f32x4*)&pb[(((quad << 2) + r) * 16 + row16) * 20 + (wave << 2)] = v;
    }
    // LDS-only barrier (no vmcnt drain)
    asm volatile("s_waitcnt lgkmcnt(0)\n\ts_barrier" ::: "memory");

    // ---- reduce: thread tid handles (m=ub, n=uc); row = tid; 4x b128 reads ----
    const int rbase = tid * 20;
    f32x4 v0 = *(const f32x4*)&pb[rbase];
    f32x4 v1 = *(const f32x4*)&pb[rbase + 4];
    f32x4 v2 = *(const f32x4*)&pb[rbase + 8];
    f32x4 v3 = *(const f32x4*)&pb[rbase + 12];
    float pre[4];
    #pragma unroll
    for (int g = 0; g < 4; ++g)
      pre[g] = bias[g] + v0[g] + v1[g] + v2[g] + v3[g];

    const float ig = 1.0f / (1.0f + __expf(-pre[0]));
    const float fg = 1.0f / (1.0f + __expf(-pre[1]));
    const float og = 1.0f / (1.0f + __expf(-pre[2]));
    const float e2  = __expf(2.0f * pre[3]);
    const float ct  = (e2 - 1.0f) / (e2 + 1.0f);
    c_reg = fg * c_reg + ig * ct;
    const float e2c = __expf(2.0f * c_reg);
    const float tc  = (e2c - 1.0f) / (e2c + 1.0f);
    const float h   = og * tc;

    // ---- EARLY PUBLISH: tagged 64-bit store issued within ~tens of cycles
    // of h. Safe by the overwrite induction (we already passed the poll for
    // tag t). Wave 3 re-publishes the identical words below (idempotent).
    if (t < T_ - 1) {
      const float hpart = __shfl_xor(h, 1);
      if ((uc & 1) == 0) {
        const uint32_t d = (uint32_t)bf16rne(h) | ((uint32_t)bf16rne(hpart) << 16);
        const uint64_t qv = (uint64_t)d | ((uint64_t)(uint32_t)(t + 1) << 32);
        const uint32_t idx = (uint32_t)((t + 1) & 1) * 32768u
                           + (uint32_t)((col0 + uc) >> 1) * 128u
                           + (uint32_t)(bg0 + ub);
        __hip_atomic_store(hbuf + idx, qv, __ATOMIC_RELAXED, __HIP_MEMORY_SCOPE_AGENT);
      }
    }

    // hand h to the store wave
    hsh[tid] = h;
    asm volatile("s_waitcnt lgkmcnt(0)\n\ts_barrier" ::: "memory");

    // ---- wave 3: rotate x, issue next x loads, re-publish, NT stores ----
    if (wave == 3) {
      // rotate: cvt the raw x(t+1) loaded a full step ago (no load stall)
      if (t + 1 < T_) {
        #pragma unroll
        for (int ki = 0; ki < 6; ++ki) afrag[ki] = cvt8(xlo[ki], xhi[ki]);
      }
      // issue raw x(t+2) BEFORE stores: later waits for these loads never
      // inherit store acks (in-order vmcnt retirement).
      if (t + 2 < T_) {
        #pragma unroll
        for (int ki = 0; ki < 6; ++ki) {
          const int k = kbase + ki * 32 + quad * 8 - 512;
          const float* xp = x + ((size_t)(bg0 + row16) * T_ + (t + 2)) * I_ + k;
          xlo[ki] = *(const float4*)xp;
          xhi[ki] = *(const float4*)(xp + 4);
        }
      }
      // gather h: lane l -> (ub=l>>2, uc=4*(l&3)..+3), one ds_read_b128
      const f32x4 hv4 = *(const f32x4*)&hsh[(lane >> 2) * 16 + (lane & 3) * 4];
      // RE-PUBLISH (R9-proven safety net; identical words -> idempotent)
      if (t < T_ - 1) {
        const uint32_t d0 = (uint32_t)bf16rne(hv4[0]) | ((uint32_t)bf16rne(hv4[1]) << 16);
        const uint32_t d1 = (uint32_t)bf16rne(hv4[2]) | ((uint32_t)bf16rne(hv4[3]) << 16);
        const uint64_t tag = ((uint64_t)(uint32_t)(t + 1)) << 32;
        const uint32_t idx0 = (uint32_t)((t + 1) & 1) * 32768u
                            + ((uint32_t)(col0 >> 1) + 2u * (uint32_t)(lane & 3)) * 128u
                            + (uint32_t)(bg0 + (lane >> 2));
        __hip_atomic_store(hbuf + idx0,       (uint64_t)d0 | tag, __ATOMIC_RELAXED, __HIP_MEMORY_SCOPE_AGENT);
        __hip_atomic_store(hbuf + idx0 + 128, (uint64_t)d1 | tag, __ATOMIC_RELAXED, __HIP_MEMORY_SCOPE_AGENT);
      }
      // hidden-seq row t (NT, 16B/lane, 64B per 4-lane cluster)
      f32x4* op = (f32x4*)&out[((size_t)(bg0 + (lane >> 2)) * T_ + t) * H_ + col0 + 4 * (lane & 3)];
      __builtin_nontemporal_store(hv4, op);
      if (t == T_ - 1) {
        f32x4* hp = (f32x4*)&out[(size_t)B_ * T_ * H_ + (size_t)(bg0 + (lane >> 2)) * H_ + col0 + 4 * (lane & 3)];
        __builtin_nontemporal_store(hv4, hp);   // h_T
      }
    }
  }

  // c_T (per-thread; after the loop, nothing polls anymore)
  __builtin_nontemporal_store(
      c_reg, &out[(size_t)B_ * T_ * H_ + (size_t)B_ * H_ + (size_t)(bg0 + ub) * H_ + (col0 + uc)]);
}

extern "C" void kernel_launch(void* const* d_in, const int* in_sizes, int n_in,
                              void* d_out, int out_size, void* d_ws, size_t ws_size,
                              hipStream_t stream) {
  // ws layout: [0, 512KB): double-buffered tagged h exchange
  //            [2 tbuf][256 colpairs][128 batches] x 8B words (tag in hi32;
  //            zeroed each launch so stale tags can never match t>=1).
  hipMemsetAsync(d_ws, 0, 2 * 256 * 128 * 8, stream);
  dim3 grid(256), block(256);
  lstm_fused<<<grid, block, 0, stream>>>(
      (const float*)d_in[0],
      (const float*)d_in[1], (const float*)d_in[2], (const float*)d_in[3],
      (const float*)d_in[4], (const float*)d_in[5], (const float*)d_in[6],
      (const float*)d_in[7], (const float*)d_in[8], (const float*)d_in[9],
      (const float*)d_in[10], (const float*)d_in[11], (const float*)d_in[12],
      (float*)d_out, (uint32_t*)d_ws);
}